// Round 2
// baseline (603.196 us; speedup 1.0000x reference)
//
#include <hip/hip_runtime.h>
#include <stdint.h>

#define HDIM 768
#define IDIM 3072
#define NROWS 25216   // 128*197
#define RPB 8         // rows per block in fused kernel
#define TPB 512       // threads per block (fused)
#define KCH 6         // IDIM / TPB

// ---------------------------------------------------------------------------
// Pass 1a: pack W sign bits + fold scales.
//   wbits layout: [wg=0..6][i][j=0..4] u32; word w=wg*4+j covers h=w*32..+31,
//   bit k <-> h=w*32+k, bit=1 <=> W>0.
//   c0[i] = sum|W[i,:]| + b[i]      (alpha*768 + b)
//   c1[i] = sum|W[i,:]| * 2/768     (2*alpha)
//   y = c0 - c1 * popcount_mismatch
// ---------------------------------------------------------------------------
__global__ __launch_bounds__(256) void wprep_kernel(
    const float* __restrict__ W, const float* __restrict__ bias,
    uint32_t* __restrict__ wbits, float* __restrict__ c0, float* __restrict__ c1)
{
    const int wv   = threadIdx.x >> 6;
    const int lane = threadIdx.x & 63;
    const int i    = blockIdx.x * 4 + wv;
    const float* wr = W + (size_t)i * HDIM;

    float sabs = 0.f;
    uint32_t myword = 0;
    #pragma unroll
    for (int c = 0; c < 12; ++c) {
        float w = wr[c * 64 + lane];
        sabs += fabsf(w);
        unsigned long long mask = __ballot(w > 0.f);
        if (lane == 2 * c)     myword = (uint32_t)mask;
        if (lane == 2 * c + 1) myword = (uint32_t)(mask >> 32);
    }
    #pragma unroll
    for (int m = 32; m; m >>= 1) sabs += __shfl_xor(sabs, m, 64);

    if (lane < 24)
        wbits[((size_t)(lane >> 2) * IDIM + i) * 4 + (lane & 3)] = myword;
    if (lane == 0) {
        c0[i] = sabs + bias[i];
        c1[i] = sabs * (2.0f / 768.0f);
    }
}

// ---------------------------------------------------------------------------
// Pass 1b: binarize activations -> xbits[row][24] u32 (bit=1 <=> x+move > 0).
// One wave per row.
// ---------------------------------------------------------------------------
__global__ __launch_bounds__(256) void xprep_kernel(
    const float* __restrict__ hid, const float* __restrict__ move,
    uint32_t* __restrict__ xbits)
{
    const int wv   = threadIdx.x >> 6;
    const int lane = threadIdx.x & 63;
    const int row  = blockIdx.x * 4 + wv;
    const float* hr = hid + (size_t)row * HDIM;

    uint32_t myword = 0;
    #pragma unroll
    for (int j = 0; j < 12; ++j) {
        int h = j * 64 + lane;
        float v = hr[h] + move[h];
        unsigned long long mask = __ballot(v > 0.f);
        if (lane == 2 * j)     myword = (uint32_t)mask;
        if (lane == 2 * j + 1) myword = (uint32_t)(mask >> 32);
    }
    if (lane < 24) xbits[(size_t)row * 24 + lane] = myword;
}

// ---------------------------------------------------------------------------
// Pass 2: fused xnor-popcount GEMM -> LayerNorm -> concat residual -> RPReLU.
// One block = 8 rows, 512 threads. x-bits come in via SGPR s_loads (uniform
// per block); wbits held in VGPRs and reused across the 8 rows.
// zro == 0 at runtime; k*zro defeats LICM hoisting of all 192 uniform loads.
// ---------------------------------------------------------------------------
__global__ __launch_bounds__(TPB) void fused_kernel(
    const float* __restrict__ hid,
    const uint32_t* __restrict__ xbits,
    const uint32_t* __restrict__ wbits,
    const float* __restrict__ c0, const float* __restrict__ c1,
    const float* __restrict__ gamma, const float* __restrict__ beta,
    const float* __restrict__ move1, const float* __restrict__ pal,
    const float* __restrict__ move2, float* __restrict__ out, int zro)
{
    __shared__ float hlds[RPB * HDIM];   // 24 KB: hidden rows for residual
    __shared__ float red[8][RPB][2];     // per-wave partial LN stats
    __shared__ float musd[RPB][2];       // mu, rstd per row

    const int tid  = threadIdx.x;
    const int wv   = tid >> 6;
    const int lane = tid & 63;
    const size_t row0 = (size_t)blockIdx.x * RPB;

    // Stage 8 hidden rows into LDS (coalesced float4). No barrier needed yet:
    // nothing reads hlds until after the LN-stats barriers.
    {
        const float4* src = (const float4*)(hid + row0 * HDIM);
        float4* dst = (float4*)hlds;
        #pragma unroll
        for (int p = 0; p < 3; ++p) dst[tid + p * TPB] = src[tid + p * TPB];
    }

    // ---- xnor-popcount GEMM: each thread 6 i-values x 8 rows ----
    float y[KCH][RPB];
    #pragma unroll
    for (int k = 0; k < KCH; ++k) {
        const int i = k * TPB + tid;
        uint32_t wb[24];
        const uint4* wp = (const uint4*)wbits;
        #pragma unroll
        for (int wg = 0; wg < 6; ++wg) {
            uint4 v = wp[(size_t)wg * IDIM + i];
            wb[4*wg+0] = v.x; wb[4*wg+1] = v.y;
            wb[4*wg+2] = v.z; wb[4*wg+3] = v.w;
        }
        const float C0 = c0[i], C1 = c1[i];
        // uniform base; k*zro (==0) makes it k-dependent so the 192 scalar
        // loads are NOT all hoisted out of the k-loop (SGPR budget ~102)
        const uint32_t* xrow = xbits + row0 * 24 + (size_t)(k * zro);
        #pragma unroll
        for (int r = 0; r < RPB; ++r) {
            int m = 0;
            #pragma unroll
            for (int w = 0; w < 24; ++w)
                m += __popc(wb[w] ^ xrow[r * 24 + w]);   // v_xor v,s,v + v_bcnt
            y[k][r] = C0 - C1 * (float)m;                // alpha*(768-2m)+b
        }
    }

    // ---- LayerNorm statistics (per row over 3072 i) ----
    #pragma unroll
    for (int r = 0; r < RPB; ++r) {
        float s = 0.f, q = 0.f;
        #pragma unroll
        for (int k = 0; k < KCH; ++k) { float v = y[k][r]; s += v; q += v * v; }
        #pragma unroll
        for (int m = 32; m; m >>= 1) {
            s += __shfl_xor(s, m, 64);
            q += __shfl_xor(q, m, 64);
        }
        if (lane == 0) { red[wv][r][0] = s; red[wv][r][1] = q; }
    }
    __syncthreads();
    if (tid < 64) {
        const int r = tid >> 3, w = tid & 7;
        float s = red[w][r][0], q = red[w][r][1];
        #pragma unroll
        for (int m = 1; m < 8; m <<= 1) {
            s += __shfl_xor(s, m, 64);
            q += __shfl_xor(q, m, 64);
        }
        if (w == 0) {
            float mu  = s * (1.0f / 3072.0f);
            float var = q * (1.0f / 3072.0f) - mu * mu;
            musd[r][0] = mu;
            musd[r][1] = rsqrtf(var + 1e-12f);
        }
    }
    __syncthreads();

    float mur[RPB], rsr[RPB];
    #pragma unroll
    for (int r = 0; r < RPB; ++r) { mur[r] = musd[r][0]; rsr[r] = musd[r][1]; }

    // ---- epilogue: LN affine + concat residual + RPReLU + store ----
    #pragma unroll
    for (int k = 0; k < KCH; ++k) {
        const int i = k * TPB + tid;
        const float g  = gamma[i], be = beta[i];
        const float m1 = move1[i], pa = pal[i], m2 = move2[i];
        const int h = i % HDIM;                 // concat([hidden]*4) index
        #pragma unroll
        for (int r = 0; r < RPB; ++r) {
            float yn = (y[k][r] - mur[r]) * rsr[r] * g + be;
            float o  = yn + hlds[r * HDIM + h];
            float z  = o - m1;
            o = (z >= 0.f ? z : pa * z) + m2;
            out[(row0 + r) * IDIM + i] = o;
        }
    }
}

// ---------------------------------------------------------------------------
extern "C" void kernel_launch(void* const* d_in, const int* in_sizes, int n_in,
                              void* d_out, int out_size, void* d_ws, size_t ws_size,
                              hipStream_t stream)
{
    const float* hs    = (const float*)d_in[0];
    const float* W     = (const float*)d_in[1];
    const float* bias  = (const float*)d_in[2];
    const float* move  = (const float*)d_in[3];
    const float* gamma = (const float*)d_in[4];
    const float* beta  = (const float*)d_in[5];
    const float* move1 = (const float*)d_in[6];
    const float* pal   = (const float*)d_in[7];
    const float* move2 = (const float*)d_in[8];
    float* out = (float*)d_out;

    // workspace layout (all 16B-aligned):
    //   xbits [NROWS*24 u32]   = 2,420,736 B
    //   wbits [6*IDIM*4 u32]   =   294,912 B
    //   c0[IDIM], c1[IDIM]     =    12,288 B each
    uint32_t* xbits = (uint32_t*)d_ws;
    uint32_t* wbits = xbits + (size_t)NROWS * 24;
    float*    c0    = (float*)(wbits + (size_t)6 * IDIM * 4);
    float*    c1    = c0 + IDIM;

    wprep_kernel<<<IDIM / 4, 256, 0, stream>>>(W, bias, wbits, c0, c1);
    xprep_kernel<<<NROWS / 4, 256, 0, stream>>>(hs, move, xbits);
    fused_kernel<<<NROWS / RPB, TPB, 0, stream>>>(
        hs, xbits, wbits, c0, c1, gamma, beta, move1, pal, move2, out, 0);
}